// Round 10
// baseline (361.427 us; speedup 1.0000x reference)
//
#include <hip/hip_runtime.h>
#include <cstdint>
#include <cstddef>

// Problem constants
#define NN    50000
#define EE    800000
#define ET    850000   /* EE + NN self-loops */
#define SLOPE 0.2f
#define MT64  782      /* (NN+63)/64 gemm row-blocks */
#define SCB   831      /* (ET+1023)/1024 scatter blocks (4 edges/thread) */
#define CAP   96       /* per-node edge bucket capacity (max in-deg ~45) */
#define LDR   72       /* LDS row stride (ushorts): 36dw -> 2-way b128 reads (free) */

typedef unsigned short ushortT;
typedef __attribute__((ext_vector_type(8))) short short8;
typedef __attribute__((ext_vector_type(4))) float floatx4;

__device__ __forceinline__ float lrelu(float x){ return x > 0.f ? x : SLOPE * x; }
__device__ __forceinline__ float eluf(float x){ return x > 0.f ? x : __expf(x) - 1.f; }
__device__ __forceinline__ ushortT f2b(float f){ unsigned u = __float_as_uint(f); u += 0x7fff + ((u >> 16) & 1); return (ushortT)(u >> 16); }
__device__ __forceinline__ float   b2f(ushortT b){ return __uint_as_float(((unsigned)b) << 16); }

__device__ __forceinline__ void edge_sd(const int* __restrict__ srcA, const int* __restrict__ dstA,
                                        int e, int& s, int& d)
{
    if (e < EE) { s = srcA[e]; d = dstA[e]; }
    else        { s = e - EE;  d = s; }
}

// ---------------------------------------------------------------------------
// GEMM body, software-pipelined: C[M, NT*16](bf16) = A[M,256] @ BT[NT*16,256]^T
// + fused attention-logit epilogue. 64 rows/block, 4 waves, K-step 64, 4 iters.
// Register prefetch: iter k+1's global slices load right after the LDS-store
// barrier and are consumed at iter k+1's store -> global latency hides behind
// 32 MFMA + ds_reads per iter. f32 A keeps raw float4 in the prefetch buffer
// (convert at store time) so no vmcnt wait blocks the prefetch issue.
// ---------------------------------------------------------------------------
template<bool A_F32, int NT, int HEADS>
__device__ __forceinline__ void gemm_body(const void* __restrict__ Aptr,
                                          const ushortT* __restrict__ BT,
                                          const float* __restrict__ attS,
                                          const float* __restrict__ attD,
                                          ushortT* __restrict__ C,
                                          float* __restrict__ asrc,
                                          float* __restrict__ adst,
                                          int M, int bId,
                                          ushortT* As, ushortT* Bs)
{
    constexpr int NCOL = NT * 16;
    constexpr int NB   = (NT == 16) ? 8 : 2;   // B prefetch regs (uint4)
    const int tid  = threadIdx.x;
    const int wave = tid >> 6;
    const int lane = tid & 63;
    const int m16  = lane & 15;
    const int quad = lane >> 4;
    const int row0 = bId * 64;
    const int arow = tid >> 2;           // 0..63
    const int acol = (tid & 3) << 4;     // 0,16,32,48 (element units)
    const long arowG = min(row0 + arow, M - 1);
    const int brow = (NT == 16) ? tid : (tid >> 2);
    const int bcol = (NT == 16) ? 0   : ((tid & 3) << 4);

    floatx4 acc[NT];
    #pragma unroll
    for (int j = 0; j < NT; ++j) acc[j] = (floatx4){0.f, 0.f, 0.f, 0.f};

    float4 fbuf[4];     // A prefetch (f32 path)
    uint4  ab[2];       // A prefetch (bf16 path)
    uint4  bbuf[NB];    // B prefetch

    auto loadA = [&](int k0) {
        if (A_F32) {
            const float* A = (const float*)Aptr;
            #pragma unroll
            for (int q = 0; q < 4; ++q)
                fbuf[q] = *(const float4*)(A + arowG * 256 + k0 + acol + q * 4);
        } else {
            const ushortT* A = (const ushortT*)Aptr;
            ab[0] = *(const uint4*)(A + arowG * 256 + k0 + acol);
            ab[1] = *(const uint4*)(A + arowG * 256 + k0 + acol + 8);
        }
    };
    auto loadB = [&](int k0) {
        const ushortT* bp = BT + (size_t)brow * 256 + k0 + bcol;
        #pragma unroll
        for (int q = 0; q < NB; ++q) bbuf[q] = *(const uint4*)(bp + q * 8);
    };
    auto storeLDS = [&]() {
        if (A_F32) {
            ushortT a16[16];
            #pragma unroll
            for (int q = 0; q < 4; ++q) {
                a16[q*4+0] = f2b(fbuf[q].x); a16[q*4+1] = f2b(fbuf[q].y);
                a16[q*4+2] = f2b(fbuf[q].z); a16[q*4+3] = f2b(fbuf[q].w);
            }
            *(uint4*)(&As[arow * LDR + acol])     = *(uint4*)(a16);
            *(uint4*)(&As[arow * LDR + acol + 8]) = *(uint4*)(a16 + 8);
        } else {
            *(uint4*)(&As[arow * LDR + acol])     = ab[0];
            *(uint4*)(&As[arow * LDR + acol + 8]) = ab[1];
        }
        #pragma unroll
        for (int q = 0; q < NB; ++q)
            *(uint4*)(&Bs[brow * LDR + bcol + q * 8]) = bbuf[q];
    };

    loadA(0); loadB(0);
    #pragma unroll
    for (int it = 0; it < 4; ++it) {
        __syncthreads();    // prev iter's LDS reads done
        storeLDS();
        __syncthreads();
        if (it < 3) { loadA((it + 1) * 64); loadB((it + 1) * 64); }  // prefetch
        short8 af0 = *(const short8*)(&As[(wave * 16 + m16) * LDR + quad * 8]);
        short8 af1 = *(const short8*)(&As[(wave * 16 + m16) * LDR + 32 + quad * 8]);
        #pragma unroll
        for (int j = 0; j < NT; ++j) {
            short8 bf0 = *(const short8*)(&Bs[(j * 16 + m16) * LDR + quad * 8]);
            short8 bf1 = *(const short8*)(&Bs[(j * 16 + m16) * LDR + 32 + quad * 8]);
            acc[j] = __builtin_amdgcn_mfma_f32_16x16x32_bf16(af0, bf0, acc[j], 0, 0, 0);
            acc[j] = __builtin_amdgcn_mfma_f32_16x16x32_bf16(af1, bf1, acc[j], 0, 0, 0);
        }
    }

    float attSv[NT], attDv[NT];
    #pragma unroll
    for (int j = 0; j < NT; ++j) {
        attSv[j] = attS[j * 16 + m16];
        attDv[j] = attD[j * 16 + m16];
    }

    #pragma unroll
    for (int r = 0; r < 4; ++r) {
        int row = row0 + wave * 16 + quad * 4 + r;
        bool ok = row < M;
        if (ok) {
            #pragma unroll
            for (int j = 0; j < NT; ++j)
                C[(size_t)row * NCOL + j * 16 + m16] = f2b(acc[j][r]);
        }
        float ds[HEADS], dd[HEADS];
        #pragma unroll
        for (int h = 0; h < HEADS; ++h) {
            float s = 0.f, d2 = 0.f;
            #pragma unroll
            for (int jj = 0; jj < 4; ++jj) {
                int j = h * 4 + jj;
                s  += acc[j][r] * attSv[j];
                d2 += acc[j][r] * attDv[j];
            }
            #pragma unroll
            for (int off = 1; off < 16; off <<= 1) {
                s  += __shfl_xor(s, off);
                d2 += __shfl_xor(d2, off);
            }
            ds[h] = s; dd[h] = d2;
        }
        if (ok && m16 == 0) {
            if (HEADS == 4) {
                *(float4*)(asrc + (size_t)row * 4) = make_float4(ds[0], ds[1], ds[2], ds[3]);
                *(float4*)(adst + (size_t)row * 4) = make_float4(dd[0], dd[1], dd[2], dd[3]);
            } else {
                asrc[row] = ds[0];
                adst[row] = dd[0];
            }
        }
    }
}

// ---------------------------------------------------------------------------
// Fused prep: blocks [0,256) cast weights; [256,..) DIRECT bucket-scatter:
// rank = atomicAdd(cnt+d,1); esorted[d*CAP+rank] = s. No prefix scan needed.
// ---------------------------------------------------------------------------
__global__ __launch_bounds__(256) void prep_k(const float* __restrict__ W1, const float* __restrict__ W2,
                                              ushortT* __restrict__ W1T, ushortT* __restrict__ W2T,
                                              const int* __restrict__ srcA, const int* __restrict__ dstA,
                                              int* __restrict__ cnt, int* __restrict__ esorted)
{
    int t = threadIdx.x;
    int b = blockIdx.x;
    if (b < 256) {
        W1T[t * 256 + b] = f2b(W1[b * 256 + t]);
        if (t < 64) W2T[t * 256 + b] = f2b(W2[b * 64 + t]);
    } else {
        int e0 = (b - 256) * 1024 + t;
        #pragma unroll
        for (int k = 0; k < 4; ++k) {
            int e = e0 + k * 256;
            if (e < ET) {
                int s, d; edge_sd(srcA, dstA, e, s, d);
                int r = atomicAdd(cnt + d, 1);
                if (r < CAP) esorted[d * CAP + r] = s;   // clamp: P(deg>CAP) ~ 1e-40
            }
        }
    }
}

// Layer-1 GEMM (f32 A inline-cast; x read exactly once)
__global__ __launch_bounds__(256, 3) void gemm1_k(const float* __restrict__ x,
                                                  const ushortT* __restrict__ W1T,
                                                  const float* __restrict__ attS,
                                                  const float* __restrict__ attD,
                                                  ushortT* __restrict__ h1b,
                                                  float* __restrict__ asrc,
                                                  float* __restrict__ adst)
{
    __shared__ ushortT As[64 * LDR];
    __shared__ ushortT Bs[256 * LDR];
    gemm_body<true, 16, 4>(x, W1T, attS, attD, h1b, asrc, adst, NN, blockIdx.x, As, Bs);
}

// Layer-2 GEMM
__global__ __launch_bounds__(256, 4) void gemm2_k(const ushortT* __restrict__ a2b,
                                                  const ushortT* __restrict__ W2T,
                                                  const float* __restrict__ attS,
                                                  const float* __restrict__ attD,
                                                  ushortT* __restrict__ t2b,
                                                  float* __restrict__ asrc,
                                                  float* __restrict__ adst)
{
    __shared__ ushortT As[64 * LDR];
    __shared__ ushortT Bs[64 * LDR];
    gemm_body<false, 4, 1>(a2b, W2T, attS, attD, t2b, asrc, adst, NN, blockIdx.x, As, Bs);
}

// ---------------------------------------------------------------------------
// agg1: chunked pass. Lane=edge computes p (4 heads) once into wave-local LDS;
// all lanes gather h1b rows weighted by LDS-broadcast p. Phase B unroll 8.
// Segment = esorted[n*CAP .. n*CAP+deg). No max-subtraction (logits O(7)).
// ---------------------------------------------------------------------------
__global__ __launch_bounds__(256) void agg1_k(const int* __restrict__ esorted,
                                              const int* __restrict__ cnt,
                                              const ushortT* __restrict__ h1b,
                                              const float* __restrict__ asrc,
                                              const float* __restrict__ adst,
                                              const float* __restrict__ b1,
                                              ushortT* __restrict__ a2b)
{
    __shared__ float pbuf[4][64][4];
    __shared__ int   sbuf[4][64];
    int w = threadIdx.x >> 6;
    int lane = threadIdx.x & 63;
    int n = blockIdx.x * 4 + w;
    if (n >= NN) return;
    int start = n * CAP;
    int deg = min(cnt[n], CAP);
    float4 adv = *(const float4*)(adst + (size_t)n * 4);
    int h = lane >> 4;
    int c4 = lane * 4;

    float4 ssv = make_float4(0.f, 0.f, 0.f, 0.f);
    float4 ac0 = make_float4(0.f,0.f,0.f,0.f);
    float4 ac1 = make_float4(0.f,0.f,0.f,0.f);
    float4 ac2 = make_float4(0.f,0.f,0.f,0.f);
    float4 ac3 = make_float4(0.f,0.f,0.f,0.f);

    for (int base = 0; base < deg; base += 64) {
        int cl = min(64, deg - base);
        int i = base + lane;
        if (i < deg) {
            int s = esorted[start + i];
            float4 a = *(const float4*)(asrc + (size_t)s * 4);
            float4 pv;
            pv.x = __expf(lrelu(a.x + adv.x));
            pv.y = __expf(lrelu(a.y + adv.y));
            pv.z = __expf(lrelu(a.z + adv.z));
            pv.w = __expf(lrelu(a.w + adv.w));
            ssv.x += pv.x; ssv.y += pv.y; ssv.z += pv.z; ssv.w += pv.w;
            *(float4*)(&pbuf[w][lane][0]) = pv;
            sbuf[w][lane] = s;
        }
        __builtin_amdgcn_wave_barrier();   // intra-wave LDS write->read ordering
        int j = 0;
        for (; j + 7 < cl; j += 8) {
            float4 hv[8]; float pp[8];
            #pragma unroll
            for (int q = 0; q < 8; ++q) {
                int sq = sbuf[w][j + q];
                pp[q] = pbuf[w][j + q][h];
                ushort4 hq = *(const ushort4*)(h1b + (size_t)sq * 256 + c4);
                hv[q] = make_float4(b2f(hq.x), b2f(hq.y), b2f(hq.z), b2f(hq.w));
            }
            #pragma unroll
            for (int q = 0; q < 8; ++q) {
                float4* ac = (q & 3) == 0 ? &ac0 : (q & 3) == 1 ? &ac1 : (q & 3) == 2 ? &ac2 : &ac3;
                ac->x += hv[q].x * pp[q]; ac->y += hv[q].y * pp[q];
                ac->z += hv[q].z * pp[q]; ac->w += hv[q].w * pp[q];
            }
        }
        for (; j < cl; ++j) {
            int s0 = sbuf[w][j];
            float p0 = pbuf[w][j][h];
            ushort4 h0 = *(const ushort4*)(h1b + (size_t)s0 * 256 + c4);
            ac0.x += b2f(h0.x) * p0; ac0.y += b2f(h0.y) * p0; ac0.z += b2f(h0.z) * p0; ac0.w += b2f(h0.w) * p0;
        }
        __builtin_amdgcn_wave_barrier();   // reads done before next chunk's writes
    }

    #pragma unroll
    for (int off = 1; off < 64; off <<= 1) {
        ssv.x += __shfl_xor(ssv.x, off); ssv.y += __shfl_xor(ssv.y, off);
        ssv.z += __shfl_xor(ssv.z, off); ssv.w += __shfl_xor(ssv.w, off);
    }
    float ssh = (h < 2) ? (h == 0 ? ssv.x : ssv.y) : (h == 2 ? ssv.z : ssv.w);
    float rdh = 1.f / ssh;

    float4 bv = *(const float4*)(b1 + c4);
    ushort4 o;
    o.x = f2b(eluf((ac0.x + ac1.x + ac2.x + ac3.x) * rdh + bv.x));
    o.y = f2b(eluf((ac0.y + ac1.y + ac2.y + ac3.y) * rdh + bv.y));
    o.z = f2b(eluf((ac0.z + ac1.z + ac2.z + ac3.z) * rdh + bv.z));
    o.w = f2b(eluf((ac0.w + ac1.w + ac2.w + ac3.w) * rdh + bv.w));
    *(ushort4*)(a2b + (size_t)n * 256 + c4) = o;
}

// ---------------------------------------------------------------------------
// agg2: same chunked-LDS structure, 1 head + bias + log_softmax. Unroll 8.
// ---------------------------------------------------------------------------
__global__ __launch_bounds__(256) void agg2_k(const int* __restrict__ esorted,
                                              const int* __restrict__ cnt,
                                              const ushortT* __restrict__ t2b,
                                              const float* __restrict__ asrc,
                                              const float* __restrict__ adst,
                                              const float* __restrict__ b2,
                                              float* __restrict__ out)
{
    __shared__ float pbuf[4][64];
    __shared__ int   sbuf[4][64];
    int w = threadIdx.x >> 6;
    int lane = threadIdx.x & 63;
    int n = blockIdx.x * 4 + w;
    if (n >= NN) return;
    int start = n * CAP;
    int deg = min(cnt[n], CAP);
    float adv = adst[n];

    float ss = 0.f;
    float a0 = 0.f, a1 = 0.f, a2 = 0.f, a3 = 0.f;

    for (int base = 0; base < deg; base += 64) {
        int cl = min(64, deg - base);
        int i = base + lane;
        if (i < deg) {
            int s = esorted[start + i];
            float p = __expf(lrelu(asrc[s] + adv));
            ss += p;
            pbuf[w][lane] = p;
            sbuf[w][lane] = s;
        }
        __builtin_amdgcn_wave_barrier();
        int j = 0;
        for (; j + 7 < cl; j += 8) {
            float tv[8]; float pp[8];
            #pragma unroll
            for (int q = 0; q < 8; ++q) {
                int sq = sbuf[w][j + q];
                pp[q] = pbuf[w][j + q];
                tv[q] = b2f(t2b[(size_t)sq * 64 + lane]);
            }
            #pragma unroll
            for (int q = 0; q < 8; ++q) {
                float* ac = (q & 3) == 0 ? &a0 : (q & 3) == 1 ? &a1 : (q & 3) == 2 ? &a2 : &a3;
                *ac += tv[q] * pp[q];
            }
        }
        for (; j < cl; ++j) {
            a0 += b2f(t2b[(size_t)sbuf[w][j] * 64 + lane]) * pbuf[w][j];
        }
        __builtin_amdgcn_wave_barrier();
    }

    #pragma unroll
    for (int off = 1; off < 64; off <<= 1) ss += __shfl_xor(ss, off);
    float v = (a0 + a1 + a2 + a3) / ss + b2[lane];

    float m2 = v;
    #pragma unroll
    for (int off = 32; off; off >>= 1) m2 = fmaxf(m2, __shfl_xor(m2, off));
    float ex = __expf(v - m2);
    float sm = ex;
    #pragma unroll
    for (int off = 32; off; off >>= 1) sm += __shfl_xor(sm, off);
    out[(size_t)n * 64 + lane] = v - m2 - __logf(sm);
}

// ---------------------------------------------------------------------------
extern "C" void kernel_launch(void* const* d_in, const int* in_sizes, int n_in,
                              void* d_out, int out_size, void* d_ws, size_t ws_size,
                              hipStream_t stream)
{
    const float* x   = (const float*)d_in[0];
    const int*   adj = (const int*)  d_in[1];
    const float* W1  = (const float*)d_in[2];
    const float* as1 = (const float*)d_in[3];
    const float* ad1 = (const float*)d_in[4];
    const float* b1  = (const float*)d_in[5];
    const float* W2  = (const float*)d_in[6];
    const float* as2 = (const float*)d_in[7];
    const float* ad2 = (const float*)d_in[8];
    const float* b2  = (const float*)d_in[9];
    float* out = (float*)d_out;

    const size_t szH1b = (size_t)NN * 256 * 2;   // 25.6 MB
    const size_t szT2b = (size_t)NN * 64 * 2;    // 6.4 MB
    const size_t szA4  = (size_t)NN * 4 * 4;     // 0.8 MB
    const size_t szA1  = (size_t)NN * 4;         // 0.2 MB
    const size_t szE   = (size_t)NN * CAP * 4;   // 19.2 MB

    char* p = (char*)d_ws;
    ushortT* h1b  = (ushortT*)p; p += szH1b;
    ushortT* a2b  = (ushortT*)p; p += szH1b;
    ushortT* t2b  = (ushortT*)p; p += szT2b;
    ushortT* W1T  = (ushortT*)p; p += 256 * 256 * 2;
    ushortT* W2T  = (ushortT*)p; p += 64 * 256 * 2;
    float* asrc1  = (float*)p; p += szA4;
    float* adst1  = (float*)p; p += szA4;
    float* asrc2  = (float*)p; p += szA1;
    float* adst2  = (float*)p; p += szA1;
    int* esorted  = (int*)p; p += szE;
    int* cnt      = (int*)p; p += szA1;

    hipMemsetAsync(cnt, 0, szA1, stream);

    const int nwb = (NN + 3) / 4;       // 12500

    // castW (blocks 0..255) + direct bucket-scatter (blocks 256..)
    prep_k<<<256 + SCB, 256, 0, stream>>>(W1, W2, W1T, W2T, adj, adj + EE, cnt, esorted);

    // Layer 1
    gemm1_k<<<MT64, 256, 0, stream>>>(x, W1T, as1, ad1, h1b, asrc1, adst1);
    agg1_k<<<nwb, 256, 0, stream>>>(esorted, cnt, h1b, asrc1, adst1, b1, a2b);

    // Layer 2
    gemm2_k<<<MT64, 256, 0, stream>>>(a2b, W2T, as2, ad2, t2b, asrc2, adst2);
    agg2_k<<<nwb, 256, 0, stream>>>(esorted, cnt, t2b, asrc2, adst2, b2, out);
}

// Round 11
// 336.208 us; speedup vs baseline: 1.0750x; 1.0750x over previous
//
#include <hip/hip_runtime.h>
#include <cstdint>
#include <cstddef>

// Problem constants
#define NN    50000
#define EE    800000
#define ET    850000   /* EE + NN self-loops */
#define SLOPE 0.2f
#define MT64  782      /* (NN+63)/64 row-blocks */
#define SCB   831      /* (ET+1023)/1024 scatter blocks (4 edges/thread) */
#define CAP   96       /* per-node edge bucket capacity (max in-deg ~45) */

typedef unsigned short ushortT;
typedef __attribute__((ext_vector_type(8))) short short8;
typedef __attribute__((ext_vector_type(4))) float floatx4;

__device__ __forceinline__ float lrelu(float x){ return x > 0.f ? x : SLOPE * x; }
__device__ __forceinline__ float eluf(float x){ return x > 0.f ? x : __expf(x) - 1.f; }
__device__ __forceinline__ ushortT f2b(float f){ unsigned u = __float_as_uint(f); u += 0x7fff + ((u >> 16) & 1); return (ushortT)(u >> 16); }
__device__ __forceinline__ float   b2f(ushortT b){ return __uint_as_float(((unsigned)b) << 16); }

__device__ __forceinline__ void edge_sd(const int* __restrict__ srcA, const int* __restrict__ dstA,
                                        int e, int& s, int& d)
{
    if (e < EE) { s = srcA[e]; d = dstA[e]; }
    else        { s = e - EE;  d = s; }
}

// ---------------------------------------------------------------------------
// Layer-1 GEMM, LDS-FREE: frags load global->register directly.
// BT is K-major, so the MFMA B-fragment (B[k=quad*8+j][n=m16]) is one
// contiguous 16B per-lane load. No LDS staging, no barriers, no conflicts.
// Block: 64 rows x 256 cols, 4 waves as 2x2; wave tile 32x128:
// af[2] + bf[8] loads per 16 MFMA (K-step 32). Head h's 64 channels live
// entirely in one wave-col -> alpha epilogue stays wave-local.
// ---------------------------------------------------------------------------
__global__ __launch_bounds__(256) void gemm1_k(const float* __restrict__ x,
                                               const ushortT* __restrict__ W1T,
                                               const float* __restrict__ attS,
                                               const float* __restrict__ attD,
                                               ushortT* __restrict__ h1b,
                                               float* __restrict__ asrc,
                                               float* __restrict__ adst)
{
    const int tid  = threadIdx.x;
    const int w    = tid >> 6;
    const int lane = tid & 63;
    const int m16  = lane & 15;
    const int quad = lane >> 4;
    const int wr   = w >> 1;      // row-wave 0..1
    const int wc   = w & 1;       // col-wave 0..1
    const int rowbase = blockIdx.x * 64 + wr * 32;
    const int colbase = wc * 128;

    const long r0 = min(rowbase + m16,      NN - 1);
    const long r1 = min(rowbase + 16 + m16, NN - 1);
    const float* a0p = x + r0 * 256 + quad * 8;
    const float* a1p = x + r1 * 256 + quad * 8;
    const ushortT* bp0 = W1T + (size_t)(colbase + m16) * 256 + quad * 8;

    floatx4 acc[2][8];
    #pragma unroll
    for (int i = 0; i < 2; ++i)
        #pragma unroll
        for (int j = 0; j < 8; ++j) acc[i][j] = (floatx4){0.f, 0.f, 0.f, 0.f};

    #pragma unroll
    for (int it = 0; it < 8; ++it) {
        const int k0 = it * 32;
        float4 fa00 = *(const float4*)(a0p + k0);
        float4 fa01 = *(const float4*)(a0p + k0 + 4);
        float4 fa10 = *(const float4*)(a1p + k0);
        float4 fa11 = *(const float4*)(a1p + k0 + 4);
        uint4 fb[8];
        #pragma unroll
        for (int j = 0; j < 8; ++j)
            fb[j] = *(const uint4*)(bp0 + (size_t)j * 16 * 256 + k0);

        ushortT a16[16];
        a16[0]=f2b(fa00.x); a16[1]=f2b(fa00.y); a16[2]=f2b(fa00.z); a16[3]=f2b(fa00.w);
        a16[4]=f2b(fa01.x); a16[5]=f2b(fa01.y); a16[6]=f2b(fa01.z); a16[7]=f2b(fa01.w);
        a16[8]=f2b(fa10.x); a16[9]=f2b(fa10.y); a16[10]=f2b(fa10.z); a16[11]=f2b(fa10.w);
        a16[12]=f2b(fa11.x); a16[13]=f2b(fa11.y); a16[14]=f2b(fa11.z); a16[15]=f2b(fa11.w);
        short8 af0 = *(short8*)(a16);
        short8 af1 = *(short8*)(a16 + 8);

        #pragma unroll
        for (int j = 0; j < 8; ++j) {
            short8 bf = *(short8*)(&fb[j]);
            acc[0][j] = __builtin_amdgcn_mfma_f32_16x16x32_bf16(af0, bf, acc[0][j], 0, 0, 0);
            acc[1][j] = __builtin_amdgcn_mfma_f32_16x16x32_bf16(af1, bf, acc[1][j], 0, 0, 0);
        }
    }

    // Epilogue: bf16 C store + wave-local attention dots (2 heads per wave-col)
    float attSv[8], attDv[8];
    #pragma unroll
    for (int j = 0; j < 8; ++j) {
        attSv[j] = attS[colbase + j * 16 + m16];
        attDv[j] = attD[colbase + j * 16 + m16];
    }

    #pragma unroll
    for (int i = 0; i < 2; ++i) {
        #pragma unroll
        for (int r = 0; r < 4; ++r) {
            int row = rowbase + i * 16 + quad * 4 + r;
            bool ok = row < NN;
            if (ok) {
                #pragma unroll
                for (int j = 0; j < 8; ++j)
                    h1b[(size_t)row * 256 + colbase + j * 16 + m16] = f2b(acc[i][j][r]);
            }
            float d0 = 0.f, d1 = 0.f, e0 = 0.f, e1 = 0.f;
            #pragma unroll
            for (int jj = 0; jj < 4; ++jj) {
                d0 += acc[i][jj][r]     * attSv[jj];
                e0 += acc[i][jj][r]     * attDv[jj];
                d1 += acc[i][jj + 4][r] * attSv[jj + 4];
                e1 += acc[i][jj + 4][r] * attDv[jj + 4];
            }
            #pragma unroll
            for (int off = 1; off < 16; off <<= 1) {
                d0 += __shfl_xor(d0, off); e0 += __shfl_xor(e0, off);
                d1 += __shfl_xor(d1, off); e1 += __shfl_xor(e1, off);
            }
            if (ok && m16 == 0) {
                int hb = row * 4 + wc * 2;
                asrc[hb] = d0; asrc[hb + 1] = d1;
                adst[hb] = e0; adst[hb + 1] = e1;
            }
        }
    }
}

// ---------------------------------------------------------------------------
// Layer-2 GEMM, LDS-free. A is bf16 (a2b) -> A-frags are also direct 16B
// per-lane loads. Wave tile 16 rows x 64 cols; 4 waves stacked = 64 rows.
// ---------------------------------------------------------------------------
__global__ __launch_bounds__(256) void gemm2_k(const ushortT* __restrict__ a2b,
                                               const ushortT* __restrict__ W2T,
                                               const float* __restrict__ attS,
                                               const float* __restrict__ attD,
                                               ushortT* __restrict__ t2b,
                                               float* __restrict__ asrc,
                                               float* __restrict__ adst)
{
    const int tid  = threadIdx.x;
    const int w    = tid >> 6;
    const int lane = tid & 63;
    const int m16  = lane & 15;
    const int quad = lane >> 4;
    const int rowbase = blockIdx.x * 64 + w * 16;

    const long r0 = min(rowbase + m16, NN - 1);
    const ushortT* ap  = a2b + r0 * 256 + quad * 8;
    const ushortT* bp0 = W2T + (size_t)m16 * 256 + quad * 8;

    floatx4 acc[4];
    #pragma unroll
    for (int j = 0; j < 4; ++j) acc[j] = (floatx4){0.f, 0.f, 0.f, 0.f};

    #pragma unroll
    for (int it = 0; it < 8; ++it) {
        const int k0 = it * 32;
        uint4 fa = *(const uint4*)(ap + k0);
        uint4 fb[4];
        #pragma unroll
        for (int j = 0; j < 4; ++j)
            fb[j] = *(const uint4*)(bp0 + (size_t)j * 16 * 256 + k0);
        short8 af = *(short8*)(&fa);
        #pragma unroll
        for (int j = 0; j < 4; ++j) {
            short8 bf = *(short8*)(&fb[j]);
            acc[j] = __builtin_amdgcn_mfma_f32_16x16x32_bf16(af, bf, acc[j], 0, 0, 0);
        }
    }

    float attSv[4], attDv[4];
    #pragma unroll
    for (int j = 0; j < 4; ++j) {
        attSv[j] = attS[j * 16 + m16];
        attDv[j] = attD[j * 16 + m16];
    }

    #pragma unroll
    for (int r = 0; r < 4; ++r) {
        int row = rowbase + quad * 4 + r;
        bool ok = row < NN;
        if (ok) {
            #pragma unroll
            for (int j = 0; j < 4; ++j)
                t2b[(size_t)row * 64 + j * 16 + m16] = f2b(acc[j][r]);
        }
        float ds = 0.f, dd = 0.f;
        #pragma unroll
        for (int j = 0; j < 4; ++j) {
            ds += acc[j][r] * attSv[j];
            dd += acc[j][r] * attDv[j];
        }
        #pragma unroll
        for (int off = 1; off < 16; off <<= 1) {
            ds += __shfl_xor(ds, off);
            dd += __shfl_xor(dd, off);
        }
        if (ok && m16 == 0) {
            asrc[row] = ds;
            adst[row] = dd;
        }
    }
}

// ---------------------------------------------------------------------------
// Fused prep: blocks [0,256) cast weights; [256,..) DIRECT bucket-scatter:
// rank = atomicAdd(cnt+d,1); esorted[d*CAP+rank] = s. No prefix scan needed.
// ---------------------------------------------------------------------------
__global__ __launch_bounds__(256) void prep_k(const float* __restrict__ W1, const float* __restrict__ W2,
                                              ushortT* __restrict__ W1T, ushortT* __restrict__ W2T,
                                              const int* __restrict__ srcA, const int* __restrict__ dstA,
                                              int* __restrict__ cnt, int* __restrict__ esorted)
{
    int t = threadIdx.x;
    int b = blockIdx.x;
    if (b < 256) {
        W1T[t * 256 + b] = f2b(W1[b * 256 + t]);
        if (t < 64) W2T[t * 256 + b] = f2b(W2[b * 64 + t]);
    } else {
        int e0 = (b - 256) * 1024 + t;
        #pragma unroll
        for (int k = 0; k < 4; ++k) {
            int e = e0 + k * 256;
            if (e < ET) {
                int s, d; edge_sd(srcA, dstA, e, s, d);
                int r = atomicAdd(cnt + d, 1);
                if (r < CAP) esorted[d * CAP + r] = s;   // clamp: P(deg>CAP) ~ 1e-40
            }
        }
    }
}

// ---------------------------------------------------------------------------
// agg1: chunked pass. Lane=edge computes p (4 heads) once into wave-local LDS;
// all lanes gather h1b rows weighted by LDS-broadcast p. Phase B unroll 8.
// Segment = esorted[n*CAP .. n*CAP+deg). No max-subtraction (logits O(7)).
// ---------------------------------------------------------------------------
__global__ __launch_bounds__(256) void agg1_k(const int* __restrict__ esorted,
                                              const int* __restrict__ cnt,
                                              const ushortT* __restrict__ h1b,
                                              const float* __restrict__ asrc,
                                              const float* __restrict__ adst,
                                              const float* __restrict__ b1,
                                              ushortT* __restrict__ a2b)
{
    __shared__ float pbuf[4][64][4];
    __shared__ int   sbuf[4][64];
    int w = threadIdx.x >> 6;
    int lane = threadIdx.x & 63;
    int n = blockIdx.x * 4 + w;
    if (n >= NN) return;
    int start = n * CAP;
    int deg = min(cnt[n], CAP);
    float4 adv = *(const float4*)(adst + (size_t)n * 4);
    int h = lane >> 4;
    int c4 = lane * 4;

    float4 ssv = make_float4(0.f, 0.f, 0.f, 0.f);
    float4 ac0 = make_float4(0.f,0.f,0.f,0.f);
    float4 ac1 = make_float4(0.f,0.f,0.f,0.f);
    float4 ac2 = make_float4(0.f,0.f,0.f,0.f);
    float4 ac3 = make_float4(0.f,0.f,0.f,0.f);

    for (int base = 0; base < deg; base += 64) {
        int cl = min(64, deg - base);
        int i = base + lane;
        if (i < deg) {
            int s = esorted[start + i];
            float4 a = *(const float4*)(asrc + (size_t)s * 4);
            float4 pv;
            pv.x = __expf(lrelu(a.x + adv.x));
            pv.y = __expf(lrelu(a.y + adv.y));
            pv.z = __expf(lrelu(a.z + adv.z));
            pv.w = __expf(lrelu(a.w + adv.w));
            ssv.x += pv.x; ssv.y += pv.y; ssv.z += pv.z; ssv.w += pv.w;
            *(float4*)(&pbuf[w][lane][0]) = pv;
            sbuf[w][lane] = s;
        }
        __builtin_amdgcn_wave_barrier();   // intra-wave LDS write->read ordering
        int j = 0;
        for (; j + 7 < cl; j += 8) {
            float4 hv[8]; float pp[8];
            #pragma unroll
            for (int q = 0; q < 8; ++q) {
                int sq = sbuf[w][j + q];
                pp[q] = pbuf[w][j + q][h];
                ushort4 hq = *(const ushort4*)(h1b + (size_t)sq * 256 + c4);
                hv[q] = make_float4(b2f(hq.x), b2f(hq.y), b2f(hq.z), b2f(hq.w));
            }
            #pragma unroll
            for (int q = 0; q < 8; ++q) {
                float4* ac = (q & 3) == 0 ? &ac0 : (q & 3) == 1 ? &ac1 : (q & 3) == 2 ? &ac2 : &ac3;
                ac->x += hv[q].x * pp[q]; ac->y += hv[q].y * pp[q];
                ac->z += hv[q].z * pp[q]; ac->w += hv[q].w * pp[q];
            }
        }
        for (; j < cl; ++j) {
            int s0 = sbuf[w][j];
            float p0 = pbuf[w][j][h];
            ushort4 h0 = *(const ushort4*)(h1b + (size_t)s0 * 256 + c4);
            ac0.x += b2f(h0.x) * p0; ac0.y += b2f(h0.y) * p0; ac0.z += b2f(h0.z) * p0; ac0.w += b2f(h0.w) * p0;
        }
        __builtin_amdgcn_wave_barrier();   // reads done before next chunk's writes
    }

    #pragma unroll
    for (int off = 1; off < 64; off <<= 1) {
        ssv.x += __shfl_xor(ssv.x, off); ssv.y += __shfl_xor(ssv.y, off);
        ssv.z += __shfl_xor(ssv.z, off); ssv.w += __shfl_xor(ssv.w, off);
    }
    float ssh = (h < 2) ? (h == 0 ? ssv.x : ssv.y) : (h == 2 ? ssv.z : ssv.w);
    float rdh = 1.f / ssh;

    float4 bv = *(const float4*)(b1 + c4);
    ushort4 o;
    o.x = f2b(eluf((ac0.x + ac1.x + ac2.x + ac3.x) * rdh + bv.x));
    o.y = f2b(eluf((ac0.y + ac1.y + ac2.y + ac3.y) * rdh + bv.y));
    o.z = f2b(eluf((ac0.z + ac1.z + ac2.z + ac3.z) * rdh + bv.z));
    o.w = f2b(eluf((ac0.w + ac1.w + ac2.w + ac3.w) * rdh + bv.w));
    *(ushort4*)(a2b + (size_t)n * 256 + c4) = o;
}

// ---------------------------------------------------------------------------
// agg2: same chunked-LDS structure, 1 head + bias + log_softmax. Unroll 8.
// ---------------------------------------------------------------------------
__global__ __launch_bounds__(256) void agg2_k(const int* __restrict__ esorted,
                                              const int* __restrict__ cnt,
                                              const ushortT* __restrict__ t2b,
                                              const float* __restrict__ asrc,
                                              const float* __restrict__ adst,
                                              const float* __restrict__ b2,
                                              float* __restrict__ out)
{
    __shared__ float pbuf[4][64];
    __shared__ int   sbuf[4][64];
    int w = threadIdx.x >> 6;
    int lane = threadIdx.x & 63;
    int n = blockIdx.x * 4 + w;
    if (n >= NN) return;
    int start = n * CAP;
    int deg = min(cnt[n], CAP);
    float adv = adst[n];

    float ss = 0.f;
    float a0 = 0.f, a1 = 0.f, a2 = 0.f, a3 = 0.f;

    for (int base = 0; base < deg; base += 64) {
        int cl = min(64, deg - base);
        int i = base + lane;
        if (i < deg) {
            int s = esorted[start + i];
            float p = __expf(lrelu(asrc[s] + adv));
            ss += p;
            pbuf[w][lane] = p;
            sbuf[w][lane] = s;
        }
        __builtin_amdgcn_wave_barrier();
        int j = 0;
        for (; j + 7 < cl; j += 8) {
            float tv[8]; float pp[8];
            #pragma unroll
            for (int q = 0; q < 8; ++q) {
                int sq = sbuf[w][j + q];
                pp[q] = pbuf[w][j + q];
                tv[q] = b2f(t2b[(size_t)sq * 64 + lane]);
            }
            #pragma unroll
            for (int q = 0; q < 8; ++q) {
                float* ac = (q & 3) == 0 ? &a0 : (q & 3) == 1 ? &a1 : (q & 3) == 2 ? &a2 : &a3;
                *ac += tv[q] * pp[q];
            }
        }
        for (; j < cl; ++j) {
            a0 += b2f(t2b[(size_t)sbuf[w][j] * 64 + lane]) * pbuf[w][j];
        }
        __builtin_amdgcn_wave_barrier();
    }

    #pragma unroll
    for (int off = 1; off < 64; off <<= 1) ss += __shfl_xor(ss, off);
    float v = (a0 + a1 + a2 + a3) / ss + b2[lane];

    float m2 = v;
    #pragma unroll
    for (int off = 32; off; off >>= 1) m2 = fmaxf(m2, __shfl_xor(m2, off));
    float ex = __expf(v - m2);
    float sm = ex;
    #pragma unroll
    for (int off = 32; off; off >>= 1) sm += __shfl_xor(sm, off);
    out[(size_t)n * 64 + lane] = v - m2 - __logf(sm);
}

// ---------------------------------------------------------------------------
extern "C" void kernel_launch(void* const* d_in, const int* in_sizes, int n_in,
                              void* d_out, int out_size, void* d_ws, size_t ws_size,
                              hipStream_t stream)
{
    const float* x   = (const float*)d_in[0];
    const int*   adj = (const int*)  d_in[1];
    const float* W1  = (const float*)d_in[2];
    const float* as1 = (const float*)d_in[3];
    const float* ad1 = (const float*)d_in[4];
    const float* b1  = (const float*)d_in[5];
    const float* W2  = (const float*)d_in[6];
    const float* as2 = (const float*)d_in[7];
    const float* ad2 = (const float*)d_in[8];
    const float* b2  = (const float*)d_in[9];
    float* out = (float*)d_out;

    const size_t szH1b = (size_t)NN * 256 * 2;   // 25.6 MB
    const size_t szT2b = (size_t)NN * 64 * 2;    // 6.4 MB
    const size_t szA4  = (size_t)NN * 4 * 4;     // 0.8 MB
    const size_t szA1  = (size_t)NN * 4;         // 0.2 MB
    const size_t szE   = (size_t)NN * CAP * 4;   // 19.2 MB

    char* p = (char*)d_ws;
    ushortT* h1b  = (ushortT*)p; p += szH1b;
    ushortT* a2b  = (ushortT*)p; p += szH1b;
    ushortT* t2b  = (ushortT*)p; p += szT2b;
    ushortT* W1T  = (ushortT*)p; p += 256 * 256 * 2;
    ushortT* W2T  = (ushortT*)p; p += 64 * 256 * 2;
    float* asrc1  = (float*)p; p += szA4;
    float* adst1  = (float*)p; p += szA4;
    float* asrc2  = (float*)p; p += szA1;
    float* adst2  = (float*)p; p += szA1;
    int* esorted  = (int*)p; p += szE;
    int* cnt      = (int*)p; p += szA1;

    hipMemsetAsync(cnt, 0, szA1, stream);

    const int nwb = (NN + 3) / 4;       // 12500

    // castW (blocks 0..255) + direct bucket-scatter (blocks 256..)
    prep_k<<<256 + SCB, 256, 0, stream>>>(W1, W2, W1T, W2T, adj, adj + EE, cnt, esorted);

    // Layer 1
    gemm1_k<<<MT64, 256, 0, stream>>>(x, W1T, as1, ad1, h1b, asrc1, adst1);
    agg1_k<<<nwb, 256, 0, stream>>>(esorted, cnt, h1b, asrc1, adst1, b1, a2b);

    // Layer 2
    gemm2_k<<<MT64, 256, 0, stream>>>(a2b, W2T, as2, ad2, t2b, asrc2, adst2);
    agg2_k<<<nwb, 256, 0, stream>>>(esorted, cnt, t2b, asrc2, adst2, b2, out);
}

// Round 12
// 287.371 us; speedup vs baseline: 1.2577x; 1.1699x over previous
//
#include <hip/hip_runtime.h>
#include <cstdint>
#include <cstddef>

// Problem constants
#define NN    50000
#define EE    800000   /* graph edges; self-loops handled analytically in agg */
#define SLOPE 0.2f
#define MT64  782      /* (NN+63)/64 row-blocks */
#define SEB   1563     /* (EE+511)/512 scatter blocks (2 edges/thread) */
#define CAP   64       /* per-node bucket capacity (in-deg Poisson(16), P(>=64)~1e-20) */

typedef unsigned short ushortT;
typedef __attribute__((ext_vector_type(8))) short short8;
typedef __attribute__((ext_vector_type(4))) float floatx4;

__device__ __forceinline__ float lrelu(float x){ return x > 0.f ? x : SLOPE * x; }
__device__ __forceinline__ float eluf(float x){ return x > 0.f ? x : __expf(x) - 1.f; }
__device__ __forceinline__ ushortT f2b(float f){ unsigned u = __float_as_uint(f); u += 0x7fff + ((u >> 16) & 1); return (ushortT)(u >> 16); }
__device__ __forceinline__ float   b2f(ushortT b){ return __uint_as_float(((unsigned)b) << 16); }

// ---------------------------------------------------------------------------
// castW: weight transpose-cast + cnt zero-init (65536 threads cover 50k ints).
// ---------------------------------------------------------------------------
__global__ __launch_bounds__(256) void castW_k(const float* __restrict__ W1, const float* __restrict__ W2,
                                               ushortT* __restrict__ W1T, ushortT* __restrict__ W2T,
                                               int* __restrict__ cnt)
{
    int k = blockIdx.x, t = threadIdx.x;
    W1T[t * 256 + k] = f2b(W1[k * 256 + t]);
    if (t < 64) W2T[t * 256 + k] = f2b(W2[k * 64 + t]);
    int i = k * 256 + t;
    if (i < NN) cnt[i] = 0;
}

// ---------------------------------------------------------------------------
// Fused: blocks [0,MT64) = layer-1 GEMM (LDS-free, global->register frags);
// blocks [MT64,..) = bucket scatter (2 edges/thread). gemm has NO LDS, so
// scatter blocks only pay the VGPR bill (~12 waves/CU at bounds(256,3)) and
// overlap gemm compute instead of serializing after it.
// ---------------------------------------------------------------------------
__global__ __launch_bounds__(256, 3) void gemmscatter_k(const float* __restrict__ x,
                                                        const ushortT* __restrict__ W1T,
                                                        const float* __restrict__ attS,
                                                        const float* __restrict__ attD,
                                                        ushortT* __restrict__ h1b,
                                                        float* __restrict__ asrc,
                                                        float* __restrict__ adst,
                                                        const int* __restrict__ srcA,
                                                        const int* __restrict__ dstA,
                                                        int* __restrict__ cnt,
                                                        ushortT* __restrict__ esorted)
{
    if (blockIdx.x >= MT64) {
        int e0 = (blockIdx.x - MT64) * 512 + threadIdx.x;
        #pragma unroll
        for (int k = 0; k < 2; ++k) {
            int e = e0 + k * 256;
            if (e < EE) {
                int s = srcA[e], d = dstA[e];
                int r = atomicAdd(cnt + d, 1);
                if (r < CAP) esorted[d * CAP + r] = (ushortT)s;
            }
        }
        return;
    }

    // ---- LDS-free GEMM1: 64x256 block, 2x2 waves, wave tile 32x128 ----
    const int tid  = threadIdx.x;
    const int w    = tid >> 6;
    const int lane = tid & 63;
    const int m16  = lane & 15;
    const int quad = lane >> 4;
    const int wr   = w >> 1;
    const int wc   = w & 1;
    const int rowbase = blockIdx.x * 64 + wr * 32;
    const int colbase = wc * 128;

    const long r0 = min(rowbase + m16,      NN - 1);
    const long r1 = min(rowbase + 16 + m16, NN - 1);
    const float* a0p = x + r0 * 256 + quad * 8;
    const float* a1p = x + r1 * 256 + quad * 8;
    const ushortT* bp0 = W1T + (size_t)(colbase + m16) * 256 + quad * 8;

    floatx4 acc[2][8];
    #pragma unroll
    for (int i = 0; i < 2; ++i)
        #pragma unroll
        for (int j = 0; j < 8; ++j) acc[i][j] = (floatx4){0.f, 0.f, 0.f, 0.f};

    #pragma unroll
    for (int it = 0; it < 8; ++it) {
        const int k0 = it * 32;
        float4 fa00 = *(const float4*)(a0p + k0);
        float4 fa01 = *(const float4*)(a0p + k0 + 4);
        float4 fa10 = *(const float4*)(a1p + k0);
        float4 fa11 = *(const float4*)(a1p + k0 + 4);
        uint4 fb[8];
        #pragma unroll
        for (int j = 0; j < 8; ++j)
            fb[j] = *(const uint4*)(bp0 + (size_t)j * 16 * 256 + k0);

        ushortT a16[16];
        a16[0]=f2b(fa00.x); a16[1]=f2b(fa00.y); a16[2]=f2b(fa00.z); a16[3]=f2b(fa00.w);
        a16[4]=f2b(fa01.x); a16[5]=f2b(fa01.y); a16[6]=f2b(fa01.z); a16[7]=f2b(fa01.w);
        a16[8]=f2b(fa10.x); a16[9]=f2b(fa10.y); a16[10]=f2b(fa10.z); a16[11]=f2b(fa10.w);
        a16[12]=f2b(fa11.x); a16[13]=f2b(fa11.y); a16[14]=f2b(fa11.z); a16[15]=f2b(fa11.w);
        short8 af0 = *(short8*)(a16);
        short8 af1 = *(short8*)(a16 + 8);

        #pragma unroll
        for (int j = 0; j < 8; ++j) {
            short8 bf = *(short8*)(&fb[j]);
            acc[0][j] = __builtin_amdgcn_mfma_f32_16x16x32_bf16(af0, bf, acc[0][j], 0, 0, 0);
            acc[1][j] = __builtin_amdgcn_mfma_f32_16x16x32_bf16(af1, bf, acc[1][j], 0, 0, 0);
        }
    }

    float attSv[8], attDv[8];
    #pragma unroll
    for (int j = 0; j < 8; ++j) {
        attSv[j] = attS[colbase + j * 16 + m16];
        attDv[j] = attD[colbase + j * 16 + m16];
    }

    #pragma unroll
    for (int i = 0; i < 2; ++i) {
        #pragma unroll
        for (int r = 0; r < 4; ++r) {
            int row = rowbase + i * 16 + quad * 4 + r;
            bool ok = row < NN;
            if (ok) {
                #pragma unroll
                for (int j = 0; j < 8; ++j)
                    h1b[(size_t)row * 256 + colbase + j * 16 + m16] = f2b(acc[i][j][r]);
            }
            float d0 = 0.f, d1 = 0.f, e0 = 0.f, e1 = 0.f;
            #pragma unroll
            for (int jj = 0; jj < 4; ++jj) {
                d0 += acc[i][jj][r]     * attSv[jj];
                e0 += acc[i][jj][r]     * attDv[jj];
                d1 += acc[i][jj + 4][r] * attSv[jj + 4];
                e1 += acc[i][jj + 4][r] * attDv[jj + 4];
            }
            #pragma unroll
            for (int off = 1; off < 16; off <<= 1) {
                d0 += __shfl_xor(d0, off); e0 += __shfl_xor(e0, off);
                d1 += __shfl_xor(d1, off); e1 += __shfl_xor(e1, off);
            }
            if (ok && m16 == 0) {
                int hb = row * 4 + wc * 2;
                asrc[hb] = d0; asrc[hb + 1] = d1;
                adst[hb] = e0; adst[hb + 1] = e1;
            }
        }
    }
}

// ---------------------------------------------------------------------------
// Layer-2 GEMM, LDS-free. Wave tile 16x64; 4 waves stacked = 64 rows.
// ---------------------------------------------------------------------------
__global__ __launch_bounds__(256) void gemm2_k(const ushortT* __restrict__ a2b,
                                               const ushortT* __restrict__ W2T,
                                               const float* __restrict__ attS,
                                               const float* __restrict__ attD,
                                               ushortT* __restrict__ t2b,
                                               float* __restrict__ asrc,
                                               float* __restrict__ adst)
{
    const int tid  = threadIdx.x;
    const int w    = tid >> 6;
    const int lane = tid & 63;
    const int m16  = lane & 15;
    const int quad = lane >> 4;
    const int rowbase = blockIdx.x * 64 + w * 16;

    const long r0 = min(rowbase + m16, NN - 1);
    const ushortT* ap  = a2b + r0 * 256 + quad * 8;
    const ushortT* bp0 = W2T + (size_t)m16 * 256 + quad * 8;

    floatx4 acc[4];
    #pragma unroll
    for (int j = 0; j < 4; ++j) acc[j] = (floatx4){0.f, 0.f, 0.f, 0.f};

    #pragma unroll
    for (int it = 0; it < 8; ++it) {
        const int k0 = it * 32;
        uint4 fa = *(const uint4*)(ap + k0);
        uint4 fb[4];
        #pragma unroll
        for (int j = 0; j < 4; ++j)
            fb[j] = *(const uint4*)(bp0 + (size_t)j * 16 * 256 + k0);
        short8 af = *(short8*)(&fa);
        #pragma unroll
        for (int j = 0; j < 4; ++j) {
            short8 bf = *(short8*)(&fb[j]);
            acc[j] = __builtin_amdgcn_mfma_f32_16x16x32_bf16(af, bf, acc[j], 0, 0, 0);
        }
    }

    float attSv[4], attDv[4];
    #pragma unroll
    for (int j = 0; j < 4; ++j) {
        attSv[j] = attS[j * 16 + m16];
        attDv[j] = attD[j * 16 + m16];
    }

    #pragma unroll
    for (int r = 0; r < 4; ++r) {
        int row = rowbase + quad * 4 + r;
        bool ok = row < NN;
        if (ok) {
            #pragma unroll
            for (int j = 0; j < 4; ++j)
                t2b[(size_t)row * 64 + j * 16 + m16] = f2b(acc[j][r]);
        }
        float ds = 0.f, dd = 0.f;
        #pragma unroll
        for (int j = 0; j < 4; ++j) {
            ds += acc[j][r] * attSv[j];
            dd += acc[j][r] * attDv[j];
        }
        #pragma unroll
        for (int off = 1; off < 16; off <<= 1) {
            ds += __shfl_xor(ds, off);
            dd += __shfl_xor(dd, off);
        }
        if (ok && m16 == 0) {
            asrc[row] = ds;
            adst[row] = dd;
        }
    }
}

// ---------------------------------------------------------------------------
// agg1: chunked pass (deg<=64 -> single chunk). Lane=edge computes p (4 heads)
// once into wave-local LDS; all lanes gather h1b rows weighted by LDS-broadcast
// p. Self-loop handled analytically (p_self, own row) - not in the bucket.
// ---------------------------------------------------------------------------
__global__ __launch_bounds__(256) void agg1_k(const ushortT* __restrict__ esorted,
                                              const int* __restrict__ cnt,
                                              const ushortT* __restrict__ h1b,
                                              const float* __restrict__ asrc,
                                              const float* __restrict__ adst,
                                              const float* __restrict__ b1,
                                              ushortT* __restrict__ a2b)
{
    __shared__ float pbuf[4][64][4];
    __shared__ int   sbuf[4][64];
    int w = threadIdx.x >> 6;
    int lane = threadIdx.x & 63;
    int n = blockIdx.x * 4 + w;
    if (n >= NN) return;
    int start = n * CAP;
    int deg = min(cnt[n], CAP);
    float4 adv = *(const float4*)(adst + (size_t)n * 4);
    float4 asf = *(const float4*)(asrc + (size_t)n * 4);
    int h = lane >> 4;
    int c4 = lane * 4;

    // self-loop term
    float4 pself;
    pself.x = __expf(lrelu(asf.x + adv.x));
    pself.y = __expf(lrelu(asf.y + adv.y));
    pself.z = __expf(lrelu(asf.z + adv.z));
    pself.w = __expf(lrelu(asf.w + adv.w));
    float psh = (h < 2) ? (h == 0 ? pself.x : pself.y) : (h == 2 ? pself.z : pself.w);

    ushort4 hsv = *(const ushort4*)(h1b + (size_t)n * 256 + c4);
    float4 ac0 = make_float4(b2f(hsv.x) * psh, b2f(hsv.y) * psh, b2f(hsv.z) * psh, b2f(hsv.w) * psh);
    float4 ac1 = make_float4(0.f,0.f,0.f,0.f);
    float4 ac2 = make_float4(0.f,0.f,0.f,0.f);
    float4 ac3 = make_float4(0.f,0.f,0.f,0.f);
    float4 ssv = make_float4(0.f, 0.f, 0.f, 0.f);

    for (int base = 0; base < deg; base += 64) {
        int cl = min(64, deg - base);
        int i = base + lane;
        if (i < deg) {
            int s = esorted[start + i];
            float4 a = *(const float4*)(asrc + (size_t)s * 4);
            float4 pv;
            pv.x = __expf(lrelu(a.x + adv.x));
            pv.y = __expf(lrelu(a.y + adv.y));
            pv.z = __expf(lrelu(a.z + adv.z));
            pv.w = __expf(lrelu(a.w + adv.w));
            ssv.x += pv.x; ssv.y += pv.y; ssv.z += pv.z; ssv.w += pv.w;
            *(float4*)(&pbuf[w][lane][0]) = pv;
            sbuf[w][lane] = s;
        }
        __builtin_amdgcn_wave_barrier();   // intra-wave LDS write->read ordering
        int j = 0;
        for (; j + 7 < cl; j += 8) {
            float4 hv[8]; float pp[8];
            #pragma unroll
            for (int q = 0; q < 8; ++q) {
                int sq = sbuf[w][j + q];
                pp[q] = pbuf[w][j + q][h];
                ushort4 hq = *(const ushort4*)(h1b + (size_t)sq * 256 + c4);
                hv[q] = make_float4(b2f(hq.x), b2f(hq.y), b2f(hq.z), b2f(hq.w));
            }
            #pragma unroll
            for (int q = 0; q < 8; ++q) {
                float4* ac = (q & 3) == 0 ? &ac0 : (q & 3) == 1 ? &ac1 : (q & 3) == 2 ? &ac2 : &ac3;
                ac->x += hv[q].x * pp[q]; ac->y += hv[q].y * pp[q];
                ac->z += hv[q].z * pp[q]; ac->w += hv[q].w * pp[q];
            }
        }
        for (; j < cl; ++j) {
            int s0 = sbuf[w][j];
            float p0 = pbuf[w][j][h];
            ushort4 h0 = *(const ushort4*)(h1b + (size_t)s0 * 256 + c4);
            ac0.x += b2f(h0.x) * p0; ac0.y += b2f(h0.y) * p0; ac0.z += b2f(h0.z) * p0; ac0.w += b2f(h0.w) * p0;
        }
        __builtin_amdgcn_wave_barrier();
    }

    #pragma unroll
    for (int off = 1; off < 64; off <<= 1) {
        ssv.x += __shfl_xor(ssv.x, off); ssv.y += __shfl_xor(ssv.y, off);
        ssv.z += __shfl_xor(ssv.z, off); ssv.w += __shfl_xor(ssv.w, off);
    }
    float ssh = (h < 2) ? (h == 0 ? ssv.x : ssv.y) : (h == 2 ? ssv.z : ssv.w);
    float rdh = 1.f / (ssh + psh);

    float4 bv = *(const float4*)(b1 + c4);
    ushort4 o;
    o.x = f2b(eluf((ac0.x + ac1.x + ac2.x + ac3.x) * rdh + bv.x));
    o.y = f2b(eluf((ac0.y + ac1.y + ac2.y + ac3.y) * rdh + bv.y));
    o.z = f2b(eluf((ac0.z + ac1.z + ac2.z + ac3.z) * rdh + bv.z));
    o.w = f2b(eluf((ac0.w + ac1.w + ac2.w + ac3.w) * rdh + bv.w));
    *(ushort4*)(a2b + (size_t)n * 256 + c4) = o;
}

// ---------------------------------------------------------------------------
// agg2: same structure, 1 head + self-loop + bias + log_softmax.
// ---------------------------------------------------------------------------
__global__ __launch_bounds__(256) void agg2_k(const ushortT* __restrict__ esorted,
                                              const int* __restrict__ cnt,
                                              const ushortT* __restrict__ t2b,
                                              const float* __restrict__ asrc,
                                              const float* __restrict__ adst,
                                              const float* __restrict__ b2,
                                              float* __restrict__ out)
{
    __shared__ float pbuf[4][64];
    __shared__ int   sbuf[4][64];
    int w = threadIdx.x >> 6;
    int lane = threadIdx.x & 63;
    int n = blockIdx.x * 4 + w;
    if (n >= NN) return;
    int start = n * CAP;
    int deg = min(cnt[n], CAP);
    float adv = adst[n];

    float pself = __expf(lrelu(asrc[n] + adv));
    float a0 = b2f(t2b[(size_t)n * 64 + lane]) * pself;
    float a1 = 0.f, a2 = 0.f, a3 = 0.f;
    float ss = 0.f;

    for (int base = 0; base < deg; base += 64) {
        int cl = min(64, deg - base);
        int i = base + lane;
        if (i < deg) {
            int s = esorted[start + i];
            float p = __expf(lrelu(asrc[s] + adv));
            ss += p;
            pbuf[w][lane] = p;
            sbuf[w][lane] = s;
        }
        __builtin_amdgcn_wave_barrier();
        int j = 0;
        for (; j + 7 < cl; j += 8) {
            float tv[8]; float pp[8];
            #pragma unroll
            for (int q = 0; q < 8; ++q) {
                int sq = sbuf[w][j + q];
                pp[q] = pbuf[w][j + q];
                tv[q] = b2f(t2b[(size_t)sq * 64 + lane]);
            }
            #pragma unroll
            for (int q = 0; q < 8; ++q) {
                float* ac = (q & 3) == 0 ? &a0 : (q & 3) == 1 ? &a1 : (q & 3) == 2 ? &a2 : &a3;
                *ac += tv[q] * pp[q];
            }
        }
        for (; j < cl; ++j) {
            a0 += b2f(t2b[(size_t)sbuf[w][j] * 64 + lane]) * pbuf[w][j];
        }
        __builtin_amdgcn_wave_barrier();
    }

    #pragma unroll
    for (int off = 1; off < 64; off <<= 1) ss += __shfl_xor(ss, off);
    float v = (a0 + a1 + a2 + a3) / (ss + pself) + b2[lane];

    float m2 = v;
    #pragma unroll
    for (int off = 32; off; off >>= 1) m2 = fmaxf(m2, __shfl_xor(m2, off));
    float ex = __expf(v - m2);
    float sm = ex;
    #pragma unroll
    for (int off = 32; off; off >>= 1) sm += __shfl_xor(sm, off);
    out[(size_t)n * 64 + lane] = v - m2 - __logf(sm);
}

// ---------------------------------------------------------------------------
extern "C" void kernel_launch(void* const* d_in, const int* in_sizes, int n_in,
                              void* d_out, int out_size, void* d_ws, size_t ws_size,
                              hipStream_t stream)
{
    const float* x   = (const float*)d_in[0];
    const int*   adj = (const int*)  d_in[1];
    const float* W1  = (const float*)d_in[2];
    const float* as1 = (const float*)d_in[3];
    const float* ad1 = (const float*)d_in[4];
    const float* b1  = (const float*)d_in[5];
    const float* W2  = (const float*)d_in[6];
    const float* as2 = (const float*)d_in[7];
    const float* ad2 = (const float*)d_in[8];
    const float* b2  = (const float*)d_in[9];
    float* out = (float*)d_out;

    const size_t szH1b = (size_t)NN * 256 * 2;   // 25.6 MB
    const size_t szT2b = (size_t)NN * 64 * 2;    // 6.4 MB
    const size_t szA4  = (size_t)NN * 4 * 4;     // 0.8 MB
    const size_t szA1  = (size_t)NN * 4;         // 0.2 MB
    const size_t szE   = (size_t)NN * CAP * 2;   // 6.4 MB (ushort buckets)

    char* p = (char*)d_ws;
    ushortT* h1b  = (ushortT*)p; p += szH1b;
    ushortT* a2b  = (ushortT*)p; p += szH1b;
    ushortT* t2b  = (ushortT*)p; p += szT2b;
    ushortT* W1T  = (ushortT*)p; p += 256 * 256 * 2;
    ushortT* W2T  = (ushortT*)p; p += 64 * 256 * 2;
    float* asrc1  = (float*)p; p += szA4;
    float* adst1  = (float*)p; p += szA4;
    float* asrc2  = (float*)p; p += szA1;
    float* adst2  = (float*)p; p += szA1;
    ushortT* esorted = (ushortT*)p; p += szE;
    int* cnt      = (int*)p; p += szA1;

    const int nwb = (NN + 3) / 4;       // 12500

    // castW + cnt zero-init (one small dispatch; no memset needed)
    castW_k<<<256, 256, 0, stream>>>(W1, W2, W1T, W2T, cnt);

    // gemm1 (blocks 0..MT64-1, LDS-free) + bucket scatter (blocks MT64..)
    gemmscatter_k<<<MT64 + SEB, 256, 0, stream>>>(x, W1T, as1, ad1, h1b, asrc1, adst1,
                                                  adj, adj + EE, cnt, esorted);

    agg1_k<<<nwb, 256, 0, stream>>>(esorted, cnt, h1b, asrc1, adst1, b1, a2b);
    gemm2_k<<<MT64, 256, 0, stream>>>(a2b, W2T, as2, ad2, t2b, asrc2, adst2);
    agg2_k<<<nwb, 256, 0, stream>>>(esorted, cnt, t2b, asrc2, adst2, b2, out);
}